// Round 1
// baseline (538.851 us; speedup 1.0000x reference)
//
#include <hip/hip_runtime.h>
#include <cstdint>
#include <cstddef>

#define NT 256

// ---------------- shared-memory layout (float offsets) ----------------
enum {
  OFF_EEGW = 0,       // 640  (8,2,20,2)
  OFF_EEGB = 640,     // 8
  OFF_PSAW = 648,     // 16   (8,2,1)
  OFF_PSAB = 664,     // 8
  OFF_LOCW = 672,     // 24   (8,3,1)
  OFF_LOCB = 696,     // 8
  OFF_TGTW = 704,     // 8    (8,1,1)
  OFF_TGTB = 712,     // 8
  OFF_NG   = 720,     // 8
  OFF_NB   = 728,     // 8
  OFF_CINW = 736,     // 192  (24,8)
  OFF_CINB = 928,     // 24
  OFF_COUTW= 952,     // 64   (8,8)
  OFF_COUTB= 1016,    // 8
  OFF_SINW = 1024,    // 192
  OFF_SINB = 1216,    // 24
  OFF_SOUTW= 1240,    // 64
  OFF_SOUTB= 1304,    // 8
  OFF_OINW = 1312,    // 192
  OFF_OINB = 1504,    // 24
  OFF_OOUTW= 1528,    // 64
  OFF_OOUTB= 1592,    // 8
  OFF_FC1B = 1600,    // 90 -> 1690
  OFF_PE30 = 1690,    // 8
  OFF_PE32 = 1698,    // 8 -> 1706 (pad 1712)
  OFF_Ebuf = 1712,    // 30*8
  OFF_Pbuf = 1952,    // 32*8
  OFF_Sbuf = 2208,    // 32*8
  OFF_Abuf = 2464,    // 32*8
  OFF_Lbuf = 2720,    // 32*8
  OFF_Tbuf = 2976,    // 32*8
  OFF_CAT  = 3232,    // 126*8 = 1008 -> 4240
  OFF_RPUP = 4240,    // 60
  OFF_RSPE = 4300,    // 60
  OFF_RACT = 4360,    // 60
  OFF_RLOC = 4420,    // 90
  OFF_RTGT = 4510,    // 30 -> 4540 (pad 4544)
  OFF_DYN  = 4544,    // 4720 (raw eeg; later reused as MHA scratch)
  SM_TOTAL = 9264,    // 37 KB
  // scratch aliased inside DYN (valid after eeg conv has consumed raw eeg)
  OFF_QP  = OFF_DYN,         // 256
  OFF_OV  = OFF_DYN + 256,   // 256
  OFF_KMM = OFF_DYN + 512,   // 16 (kmax[8], kmin[8])
  OFF_KVP = OFF_DYN + 528,   // 126*16 = 2016 interleaved k,v
  OFF_O32 = OFF_DYN + 2544,  // 256
  OFF_FCO = OFF_DYN + 2800,  // 90
};

struct MhaDesc { int Lq, Lk, qoff, kvoff, wset, dst1, dst2; };

#define EB 0
#define PB 30
#define AB 62
#define SB 94
static __device__ const MhaDesc g_desc[19] = {
  {30, 32, OFF_Ebuf, OFF_Pbuf, 0, EB, -1},   // cross(e,p)
  {30, 32, OFF_Ebuf, OFF_Abuf, 0, EB, -1},   // cross(e,a)
  {30, 32, OFF_Ebuf, OFF_Lbuf, 0, EB, -1},   // cross(e,l)
  {30, 30, OFF_Ebuf, OFF_Ebuf, 1, EB, -1},   // selfa(e)
  {30, 32, OFF_Ebuf, OFF_Sbuf, 0, EB, -1},   // cross(e,s)
  {32, 30, OFF_Pbuf, OFF_Ebuf, 0, PB, -1},   // cross(p,e)
  {32, 32, OFF_Pbuf, OFF_Abuf, 0, PB, -1},   // cross(p,a)
  {32, 32, OFF_Pbuf, OFF_Lbuf, 0, PB, -1},   // cross(p,l)
  {32, 32, OFF_Pbuf, OFF_Pbuf, 1, PB, -1},   // selfa(p)
  {32, 32, OFF_Pbuf, OFF_Sbuf, 0, PB, -1},   // cross(p,s)
  {32, 30, OFF_Sbuf, OFF_Ebuf, 0, SB, -1},   // cross(s,e)
  {32, 32, OFF_Sbuf, OFF_Pbuf, 0, SB, -1},   // cross(s,p)
  {32, 32, OFF_Sbuf, OFF_Abuf, 0, SB, -1},   // cross(s,a)
  {32, 32, OFF_Sbuf, OFF_Lbuf, 0, SB, AB},   // cross(s,l) -> speech AND action
  {32, 30, OFF_Abuf, OFF_Ebuf, 0, AB, -1},   // cross(a,e)
  {32, 32, OFF_Abuf, OFF_Pbuf, 0, AB, -1},   // cross(a,p)
  {32, 32, OFF_Abuf, OFF_Abuf, 1, AB, -1},   // selfa(a)
  {32, 32, OFF_Abuf, OFF_Sbuf, 0, AB, -1},   // cross(a,s)
  {32, 126, OFF_Tbuf, OFF_CAT, 2, -1, -1},   // out = mha(t, concat)
};

__device__ __forceinline__ float grp8_sum(float v) {
  v += __shfl_xor(v, 1);
  v += __shfl_xor(v, 2);
  v += __shfl_xor(v, 4);
  return v;
}

__global__ __launch_bounds__(NT, 4) void cmt_kernel(
    const float* __restrict__ eeg, const float* __restrict__ pupil,
    const float* __restrict__ speech, const float* __restrict__ action,
    const float* __restrict__ location, const float* __restrict__ tgt,
    const float* __restrict__ eeg_w, const float* __restrict__ eeg_b,
    const float* __restrict__ psa_w, const float* __restrict__ psa_b,
    const float* __restrict__ loc_w, const float* __restrict__ loc_b,
    const float* __restrict__ tgt_w, const float* __restrict__ tgt_b,
    const float* __restrict__ ng, const float* __restrict__ nb,
    const float* __restrict__ cin_w, const float* __restrict__ cin_b,
    const float* __restrict__ cout_w, const float* __restrict__ cout_b,
    const float* __restrict__ sin_w, const float* __restrict__ sin_b,
    const float* __restrict__ sout_w, const float* __restrict__ sout_b,
    const float* __restrict__ oin_w, const float* __restrict__ oin_b,
    const float* __restrict__ oout_w, const float* __restrict__ oout_b,
    const float* __restrict__ fc1_w, const float* __restrict__ fc1_b,
    float* __restrict__ out)
{
  __shared__ float sm[SM_TOTAL];
  const int tid = threadIdx.x;
  const int b = blockIdx.x;

#define CP(off, p, n) for (int i = tid; i < (n); i += NT) sm[(off)+i] = (p)[i]

  // ---------- phase 0: stage weights + inputs ----------
  CP(OFF_EEGW, eeg_w, 640);  CP(OFF_EEGB, eeg_b, 8);
  CP(OFF_PSAW, psa_w, 16);   CP(OFF_PSAB, psa_b, 8);
  CP(OFF_LOCW, loc_w, 24);   CP(OFF_LOCB, loc_b, 8);
  CP(OFF_TGTW, tgt_w, 8);    CP(OFF_TGTB, tgt_b, 8);
  CP(OFF_NG, ng, 8);         CP(OFF_NB, nb, 8);
  CP(OFF_CINW, cin_w, 192);  CP(OFF_CINB, cin_b, 24);
  CP(OFF_COUTW, cout_w, 64); CP(OFF_COUTB, cout_b, 8);
  CP(OFF_SINW, sin_w, 192);  CP(OFF_SINB, sin_b, 24);
  CP(OFF_SOUTW, sout_w, 64); CP(OFF_SOUTB, sout_b, 8);
  CP(OFF_OINW, oin_w, 192);  CP(OFF_OINB, oin_b, 24);
  CP(OFF_OOUTW, oout_w, 64); CP(OFF_OOUTB, oout_b, 8);
  CP(OFF_FC1B, fc1_b, 90);
  CP(OFF_DYN, eeg + (size_t)b * 4720, 4720);
  CP(OFF_RPUP, pupil + (size_t)b * 60, 60);
  CP(OFF_RSPE, speech + (size_t)b * 60, 60);
  CP(OFF_RACT, action + (size_t)b * 60, 60);
  CP(OFF_RLOC, location + (size_t)b * 90, 90);
  CP(OFF_RTGT, tgt + (size_t)b * 30, 30);
  for (int i = tid; i < 1008; i += NT) sm[OFF_CAT + i] = 0.f;
  if (tid < 16) {
    // pe_row(pos): [sin(p),cos(p),sin(.1p),cos(.1p),sin(.01p),cos(.01p),sin(.001p),cos(.001p)]
    const float divs[4] = {1.f, 0.1f, 0.01f, 0.001f};
    float pos = (tid < 8) ? 30.f : 32.f;
    int e = tid & 7;
    float x = pos * divs[e >> 1];
    float v = (e & 1) ? cosf(x) : sinf(x);
    sm[((tid < 8) ? OFF_PE30 : OFF_PE32) + e] = v;
  }
  __syncthreads();

  // ---------- phase 1: convs + positional encoding ----------
  if (tid < 240) {  // eeg conv2d: (2,20,118) * (8,2,20,2) stride (1,4) -> e[30][8]
    int w = tid >> 3, o = tid & 7;
    const float* wg = sm + OFF_EEGW + o * 80;
    float acc = sm[OFF_EEGB + o];
    #pragma unroll
    for (int i = 0; i < 2; i++)
      #pragma unroll
      for (int kh = 0; kh < 20; kh++) {
        const float* x = sm + OFF_DYN + i * 2360 + kh * 118 + 4 * w;
        const float* ww = wg + i * 40 + kh * 2;
        acc = fmaf(x[0], ww[0], fmaf(x[1], ww[1], acc));
      }
    sm[OFF_Ebuf + tid] = acc + sm[OFF_PE30 + o];
  }
  {  // conv1d k=1 pad=1 -> length-32 sequences, + pe32
    int t = tid >> 3, o = tid & 7;
    bool inb = (t >= 1 && t <= 30);
    int ti = t - 1;
    float pe = sm[OFF_PE32 + o];
    float w0 = sm[OFF_PSAW + o * 2], w1 = sm[OFF_PSAW + o * 2 + 1];
    float pb = sm[OFF_PSAB + o];
    float vp = pb, vs = pb, va = pb;
    if (inb) {
      vp = fmaf(sm[OFF_RPUP + ti], w0, fmaf(sm[OFF_RPUP + 30 + ti], w1, vp));
      vs = fmaf(sm[OFF_RSPE + ti], w0, fmaf(sm[OFF_RSPE + 30 + ti], w1, vs));
      va = fmaf(sm[OFF_RACT + ti], w0, fmaf(sm[OFF_RACT + 30 + ti], w1, va));
    }
    sm[OFF_Pbuf + tid] = vp + pe;
    sm[OFF_Sbuf + tid] = vs + pe;
    sm[OFF_Abuf + tid] = va + pe;
    float vl = sm[OFF_LOCB + o];
    if (inb) {
      vl = fmaf(sm[OFF_RLOC + ti],      sm[OFF_LOCW + o * 3],     vl);
      vl = fmaf(sm[OFF_RLOC + 30 + ti], sm[OFF_LOCW + o * 3 + 1], vl);
      vl = fmaf(sm[OFF_RLOC + 60 + ti], sm[OFF_LOCW + o * 3 + 2], vl);
    }
    sm[OFF_Lbuf + tid] = vl + pe;
    float vt = sm[OFF_TGTB + o];
    if (inb) vt = fmaf(sm[OFF_RTGT + ti], sm[OFF_TGTW + o], vt);
    sm[OFF_Tbuf + tid] = vt + pe;
  }
  __syncthreads();

  // ---------- phase 2: 18 cross/self MHAs + final MHA ----------
  for (int mi = 0; mi < 19; mi++) {
    const MhaDesc d = g_desc[mi];
    int winO, binO, woutO, boutO;
    if (d.wset == 0)      { winO = OFF_CINW; binO = OFF_CINB; woutO = OFF_COUTW; boutO = OFF_COUTB; }
    else if (d.wset == 1) { winO = OFF_SINW; binO = OFF_SINB; woutO = OFF_SOUTW; boutO = OFF_SOUTB; }
    else                  { winO = OFF_OINW; binO = OFF_OINB; woutO = OFF_OOUTW; boutO = OFF_OOUTB; }

    // q / k / v projections (head_dim=1 => qp[r][h] etc.)
    for (int idx = tid; idx < d.Lq * 8; idx += NT) {
      int r = idx >> 3, h = idx & 7;
      const float* x = sm + d.qoff + r * 8;
      const float* w = sm + winO + h * 8;
      float a = sm[binO + h];
      #pragma unroll
      for (int e = 0; e < 8; e++) a = fmaf(x[e], w[e], a);
      sm[OFF_QP + idx] = a;
    }
    for (int idx = tid; idx < d.Lk * 8; idx += NT) {
      int r = idx >> 3, h = idx & 7;
      const float* x = sm + d.kvoff + r * 8;
      const float* wk = sm + winO + 64 + h * 8;
      const float* wv = sm + winO + 128 + h * 8;
      float ak = sm[binO + 8 + h], av = sm[binO + 16 + h];
      #pragma unroll
      for (int e = 0; e < 8; e++) { ak = fmaf(x[e], wk[e], ak); av = fmaf(x[e], wv[e], av); }
      sm[OFF_KVP + r * 16 + h * 2]     = ak;
      sm[OFF_KVP + r * 16 + h * 2 + 1] = av;
    }
    __syncthreads();

    // per-head k extrema: softmax max is q*kmax (q>=0) or q*kmin (q<0)
    {
      int h = tid >> 5, j = tid & 31;
      float mx = -1e30f, mn = 1e30f;
      for (int k = j; k < d.Lk; k += 32) {
        float kv = sm[OFF_KVP + k * 16 + h * 2];
        mx = fmaxf(mx, kv); mn = fminf(mn, kv);
      }
      #pragma unroll
      for (int s = 16; s; s >>= 1) {
        mx = fmaxf(mx, __shfl_xor(mx, s));
        mn = fminf(mn, __shfl_xor(mn, s));
      }
      if (j == 0) { sm[OFF_KMM + h] = mx; sm[OFF_KMM + 8 + h] = mn; }
    }
    __syncthreads();

    // attention: one (qi,h) per thread, single exp pass
    if (tid < d.Lq * 8) {
      int h = tid & 7;
      float q = sm[OFF_QP + tid];
      float m = (q >= 0.f) ? q * sm[OFF_KMM + h] : q * sm[OFF_KMM + 8 + h];
      float l = 0.f, acc = 0.f;
      for (int k = 0; k < d.Lk; k++) {
        float kk = sm[OFF_KVP + k * 16 + h * 2];
        float vv = sm[OFF_KVP + k * 16 + h * 2 + 1];
        float ex = __expf(fmaf(q, kk, -m));
        l += ex;
        acc = fmaf(ex, vv, acc);
      }
      sm[OFF_OV + tid] = acc / l;
    }
    __syncthreads();

    // output projection + layernorm + accumulate into concat
    if (tid < d.Lq * 8) {
      int qi = tid >> 3, e = tid & 7;
      const float* o = sm + OFF_OV + qi * 8;
      float a = sm[boutO + e];
      #pragma unroll
      for (int h = 0; h < 8; h++) a = fmaf(o[h], sm[woutO + e * 8 + h], a);
      if (d.dst1 >= 0) {
        float mu = grp8_sum(a) * 0.125f;
        float dd = a - mu;
        float var = grp8_sum(dd * dd) * 0.125f;
        float nv = fmaf(dd * rsqrtf(var + 1e-5f), sm[OFF_NG + e], sm[OFF_NB + e]);
        sm[OFF_CAT + (d.dst1 + qi) * 8 + e] += nv;
        if (d.dst2 >= 0) sm[OFF_CAT + (d.dst2 + qi) * 8 + e] += nv;
      } else {
        sm[OFF_O32 + tid] = a;  // final MHA: raw output (32,8)
      }
    }
    __syncthreads();
  }

  // ---------- phase 3: fc1 + channel softmax ----------
  if (tid < 90) {
    float acc = sm[OFF_FC1B + tid];
    const float* w = fc1_w + tid * 256;
    #pragma unroll 8
    for (int k = 0; k < 256; k++) acc = fmaf(sm[OFF_O32 + k], w[k], acc);
    sm[OFF_FCO + tid] = acc;
  }
  __syncthreads();
  if (tid < 30) {
    float x0 = sm[OFF_FCO + 3 * tid], x1 = sm[OFF_FCO + 3 * tid + 1], x2 = sm[OFF_FCO + 3 * tid + 2];
    float m = fmaxf(x0, fmaxf(x1, x2));
    float e0 = __expf(x0 - m), e1 = __expf(x1 - m), e2 = __expf(x2 - m);
    float inv = 1.f / (e0 + e1 + e2);
    float* op = out + (size_t)b * 90;
    op[tid]      = e0 * inv;   // out[b][0][t]
    op[30 + tid] = e1 * inv;   // out[b][1][t]
    op[60 + tid] = e2 * inv;   // out[b][2][t]
  }
#undef CP
}

extern "C" void kernel_launch(void* const* d_in, const int* in_sizes, int n_in,
                              void* d_out, int out_size, void* d_ws, size_t ws_size,
                              hipStream_t stream) {
  (void)n_in; (void)out_size; (void)d_ws; (void)ws_size;
  int B = in_sizes[0] / 4720;  // eeg = (B,2,20,118)
  cmt_kernel<<<B, NT, 0, stream>>>(
      (const float*)d_in[0],  (const float*)d_in[1],  (const float*)d_in[2],
      (const float*)d_in[3],  (const float*)d_in[4],  (const float*)d_in[5],
      (const float*)d_in[6],  (const float*)d_in[7],  (const float*)d_in[8],
      (const float*)d_in[9],  (const float*)d_in[10], (const float*)d_in[11],
      (const float*)d_in[12], (const float*)d_in[13], (const float*)d_in[14],
      (const float*)d_in[15], (const float*)d_in[16], (const float*)d_in[17],
      (const float*)d_in[18], (const float*)d_in[19], (const float*)d_in[20],
      (const float*)d_in[21], (const float*)d_in[22], (const float*)d_in[23],
      (const float*)d_in[24], (const float*)d_in[25], (const float*)d_in[26],
      (const float*)d_in[27], (const float*)d_in[28], (const float*)d_in[29],
      (float*)d_out);
}

// Round 2
// 408.693 us; speedup vs baseline: 1.3185x; 1.3185x over previous
//
#include <hip/hip_runtime.h>
#include <cstdint>
#include <cstddef>

#define NT 256
#define LOG2E 1.4426950408889634f

#if defined(__has_builtin)
#  if __has_builtin(__builtin_amdgcn_exp2f)
#    define EXP2F(x) __builtin_amdgcn_exp2f(x)
#  else
#    define EXP2F(x) exp2f(x)
#  endif
#else
#  define EXP2F(x) exp2f(x)
#endif

// ---------------- shared-memory layout (float offsets) ----------------
enum {
  OFF_EEGW = 0,       // 640  transposed: [ik][c][o] = [(i*20+kh)*16 + c*8 + o]
  OFF_EEGB = 640,     // 8
  OFF_PSAW = 648,     // 16
  OFF_PSAB = 664,     // 8
  OFF_LOCW = 672,     // 24
  OFF_LOCB = 696,     // 8
  OFF_TGTW = 704,     // 8
  OFF_TGTB = 712,     // 8
  OFF_NG   = 720,     // 8
  OFF_NB   = 728,     // 8
  OFF_CINW = 736,     // 192 (q-rows pre-scaled by log2e)
  OFF_CINB = 928,     // 24  (q-bias pre-scaled)
  OFF_COUTW= 952,     // 64
  OFF_COUTB= 1016,    // 8
  OFF_SINW = 1024,    // 192
  OFF_SINB = 1216,    // 24
  OFF_SOUTW= 1240,    // 64
  OFF_SOUTB= 1304,    // 8
  OFF_OINW = 1312,    // 192
  OFF_OINB = 1504,    // 24
  OFF_OOUTW= 1528,    // 64
  OFF_OOUTB= 1592,    // 8
  OFF_FC1B = 1600,    // 90 -> 1690
  OFF_PE30 = 1690,    // 8
  OFF_PE32 = 1698,    // 8 -> 1706 (pad to 16B align)
  OFF_Ebuf = 1712,    // 30*8
  OFF_Pbuf = 1952,    // 32*8
  OFF_Sbuf = 2208,    // 32*8
  OFF_Abuf = 2464,    // 32*8
  OFF_Lbuf = 2720,    // 32*8
  OFF_Tbuf = 2976,    // 32*8
  OFF_CAT  = 3232,    // 126*8 -> 4240
  OFF_QP   = 4240,    // 256 (final MHA reuses as O32)
  OFF_KVP  = 4496,    // 126*16 = 2016 interleaved k,v -> 6512
  OFF_FCO  = 6512,    // 90 -> 6602
  SM_TOTAL = 6604,    // 26416 B -> 6 blocks/CU
};

struct MhaDesc { int Lq, Lk, qoff, kvoff, wset, dst1, dst2; };

#define EB 0
#define PB 30
#define AB 62
#define SB 94
static __device__ const MhaDesc g_desc[19] = {
  {30, 32, OFF_Ebuf, OFF_Pbuf, 0, EB, -1},   // cross(e,p)
  {30, 32, OFF_Ebuf, OFF_Abuf, 0, EB, -1},   // cross(e,a)
  {30, 32, OFF_Ebuf, OFF_Lbuf, 0, EB, -1},   // cross(e,l)
  {30, 30, OFF_Ebuf, OFF_Ebuf, 1, EB, -1},   // selfa(e)
  {30, 32, OFF_Ebuf, OFF_Sbuf, 0, EB, -1},   // cross(e,s)
  {32, 30, OFF_Pbuf, OFF_Ebuf, 0, PB, -1},   // cross(p,e)
  {32, 32, OFF_Pbuf, OFF_Abuf, 0, PB, -1},   // cross(p,a)
  {32, 32, OFF_Pbuf, OFF_Lbuf, 0, PB, -1},   // cross(p,l)
  {32, 32, OFF_Pbuf, OFF_Pbuf, 1, PB, -1},   // selfa(p)
  {32, 32, OFF_Pbuf, OFF_Sbuf, 0, PB, -1},   // cross(p,s)
  {32, 30, OFF_Sbuf, OFF_Ebuf, 0, SB, -1},   // cross(s,e)
  {32, 32, OFF_Sbuf, OFF_Pbuf, 0, SB, -1},   // cross(s,p)
  {32, 32, OFF_Sbuf, OFF_Abuf, 0, SB, -1},   // cross(s,a)
  {32, 32, OFF_Sbuf, OFF_Lbuf, 0, SB, AB},   // cross(s,l) -> speech AND action
  {32, 30, OFF_Abuf, OFF_Ebuf, 0, AB, -1},   // cross(a,e)
  {32, 32, OFF_Abuf, OFF_Pbuf, 0, AB, -1},   // cross(a,p)
  {32, 32, OFF_Abuf, OFF_Abuf, 1, AB, -1},   // selfa(a)
  {32, 32, OFF_Abuf, OFF_Sbuf, 0, AB, -1},   // cross(a,s)
  {32, 126, OFF_Tbuf, OFF_CAT, 2, -1, -1},   // out = mha(t, concat)
};

__device__ __forceinline__ float grp8_sum(float v) {
  v += __shfl_xor(v, 1);
  v += __shfl_xor(v, 2);
  v += __shfl_xor(v, 4);
  return v;
}

__global__ __launch_bounds__(NT, 6) void cmt_kernel(
    const float* __restrict__ eeg, const float* __restrict__ pupil,
    const float* __restrict__ speech, const float* __restrict__ action,
    const float* __restrict__ location, const float* __restrict__ tgt,
    const float* __restrict__ eeg_w, const float* __restrict__ eeg_b,
    const float* __restrict__ psa_w, const float* __restrict__ psa_b,
    const float* __restrict__ loc_w, const float* __restrict__ loc_b,
    const float* __restrict__ tgt_w, const float* __restrict__ tgt_b,
    const float* __restrict__ ng, const float* __restrict__ nb,
    const float* __restrict__ cin_w, const float* __restrict__ cin_b,
    const float* __restrict__ cout_w, const float* __restrict__ cout_b,
    const float* __restrict__ sin_w, const float* __restrict__ sin_b,
    const float* __restrict__ sout_w, const float* __restrict__ sout_b,
    const float* __restrict__ oin_w, const float* __restrict__ oin_b,
    const float* __restrict__ oout_w, const float* __restrict__ oout_b,
    const float* __restrict__ fc1_w, const float* __restrict__ fc1_b,
    float* __restrict__ out)
{
  __shared__ float sm[SM_TOTAL];
  const int tid = threadIdx.x;
  const int b = blockIdx.x;

#define CP(off, p, n) for (int i = tid; i < (n); i += NT) sm[(off)+i] = (p)[i]
#define CPQ(off, p, n, nq) for (int i = tid; i < (n); i += NT) sm[(off)+i] = (p)[i] * ((i < (nq)) ? LOG2E : 1.0f)

  // ---------- phase 0: stage weights (inputs are read direct-from-global) ----------
  // eeg weights transposed: dst[(ik*2+c)*8+o] = src[o*80 + ik*2 + c]
  for (int i = tid; i < 640; i += NT) sm[OFF_EEGW + i] = eeg_w[(i & 7) * 80 + (i >> 3)];
  CP(OFF_EEGB, eeg_b, 8);
  CP(OFF_PSAW, psa_w, 16);   CP(OFF_PSAB, psa_b, 8);
  CP(OFF_LOCW, loc_w, 24);   CP(OFF_LOCB, loc_b, 8);
  CP(OFF_TGTW, tgt_w, 8);    CP(OFF_TGTB, tgt_b, 8);
  CP(OFF_NG, ng, 8);         CP(OFF_NB, nb, 8);
  CPQ(OFF_CINW, cin_w, 192, 64);  CPQ(OFF_CINB, cin_b, 24, 8);
  CP(OFF_COUTW, cout_w, 64); CP(OFF_COUTB, cout_b, 8);
  CPQ(OFF_SINW, sin_w, 192, 64);  CPQ(OFF_SINB, sin_b, 24, 8);
  CP(OFF_SOUTW, sout_w, 64); CP(OFF_SOUTB, sout_b, 8);
  CPQ(OFF_OINW, oin_w, 192, 64);  CPQ(OFF_OINB, oin_b, 24, 8);
  CP(OFF_OOUTW, oout_w, 64); CP(OFF_OOUTB, oout_b, 8);
  CP(OFF_FC1B, fc1_b, 90);
  for (int i = tid; i < 1008; i += NT) sm[OFF_CAT + i] = 0.f;
  if (tid < 16) {
    const float divs[4] = {1.f, 0.1f, 0.01f, 0.001f};
    float pos = (tid < 8) ? 30.f : 32.f;
    int e = tid & 7;
    float x = pos * divs[e >> 1];
    float v = (e & 1) ? cosf(x) : sinf(x);
    sm[((tid < 8) ? OFF_PE30 : OFF_PE32) + e] = v;
  }
  __syncthreads();

  // ---------- phase 1: convs + positional encoding (inputs direct from global) ----------
  if (tid < 240) {  // eeg conv2d -> e[30][8]
    int w = tid >> 3, o = tid & 7;
    const float* ep = eeg + (size_t)b * 4720 + 4 * w;
    const float* wt = sm + OFF_EEGW + o;
    float acc = sm[OFF_EEGB + o];
    #pragma unroll
    for (int i = 0; i < 2; i++)
      #pragma unroll
      for (int kh = 0; kh < 20; kh++) {
        float2 x = *(const float2*)(ep + i * 2360 + kh * 118);
        int ik = i * 20 + kh;
        acc = fmaf(x.x, wt[ik * 16], fmaf(x.y, wt[ik * 16 + 8], acc));
      }
    sm[OFF_Ebuf + w * 8 + o] = acc + sm[OFF_PE30 + o];
  }
  {  // conv1d k=1 pad=1 -> length-32 sequences, + pe32
    int t = tid >> 3, o = tid & 7;
    bool inb = (t >= 1 && t <= 30);
    int ti = t - 1;
    float pe = sm[OFF_PE32 + o];
    float w0 = sm[OFF_PSAW + 2 * o], w1 = sm[OFF_PSAW + 2 * o + 1];
    float pb = sm[OFF_PSAB + o];
    float vp = pb, vs = pb, va = pb;
    float vl = sm[OFF_LOCB + o], vt = sm[OFF_TGTB + o];
    if (inb) {
      const float* pp = pupil    + (size_t)b * 60 + ti;
      const float* sp = speech   + (size_t)b * 60 + ti;
      const float* ap = action   + (size_t)b * 60 + ti;
      const float* lp = location + (size_t)b * 90 + ti;
      vp = fmaf(pp[0], w0, fmaf(pp[30], w1, vp));
      vs = fmaf(sp[0], w0, fmaf(sp[30], w1, vs));
      va = fmaf(ap[0], w0, fmaf(ap[30], w1, va));
      vl = fmaf(lp[0],  sm[OFF_LOCW + 3 * o],     vl);
      vl = fmaf(lp[30], sm[OFF_LOCW + 3 * o + 1], vl);
      vl = fmaf(lp[60], sm[OFF_LOCW + 3 * o + 2], vl);
      vt = fmaf(tgt[(size_t)b * 30 + ti], sm[OFF_TGTW + o], vt);
    }
    sm[OFF_Pbuf + tid] = vp + pe;
    sm[OFF_Sbuf + tid] = vs + pe;
    sm[OFF_Abuf + tid] = va + pe;
    sm[OFF_Lbuf + tid] = vl + pe;
    sm[OFF_Tbuf + tid] = vt + pe;
  }
  __syncthreads();

  // ---------- phase 2: 19 MHAs, 2 syncs each ----------
  for (int mi = 0; mi < 19; mi++) {
    const MhaDesc d = g_desc[mi];
    int winO, binO, woutO, boutO;
    if (d.wset == 0)      { winO = OFF_CINW; binO = OFF_CINB; woutO = OFF_COUTW; boutO = OFF_COUTB; }
    else if (d.wset == 1) { winO = OFF_SINW; binO = OFF_SINB; woutO = OFF_SOUTW; boutO = OFF_SOUTB; }
    else                  { winO = OFF_OINW; binO = OFF_OINB; woutO = OFF_OOUTW; boutO = OFF_OOUTB; }

    // q projection (weights pre-scaled by log2e)
    if (tid < d.Lq * 8) {
      int r = tid >> 3, h = tid & 7;
      const float4* x4 = (const float4*)(sm + d.qoff + r * 8);
      const float4* w4 = (const float4*)(sm + winO + h * 8);
      float4 xa = x4[0], xb = x4[1], wa = w4[0], wb = w4[1];
      float a = sm[binO + h];
      a = fmaf(xa.x, wa.x, a); a = fmaf(xa.y, wa.y, a);
      a = fmaf(xa.z, wa.z, a); a = fmaf(xa.w, wa.w, a);
      a = fmaf(xb.x, wb.x, a); a = fmaf(xb.y, wb.y, a);
      a = fmaf(xb.z, wb.z, a); a = fmaf(xb.w, wb.w, a);
      sm[OFF_QP + tid] = a;
    }
    // k,v projection, interleaved store
    for (int idx = tid; idx < d.Lk * 8; idx += NT) {
      int r = idx >> 3, h = idx & 7;
      const float4* x4 = (const float4*)(sm + d.kvoff + r * 8);
      const float4* k4 = (const float4*)(sm + winO + 64 + h * 8);
      const float4* v4 = (const float4*)(sm + winO + 128 + h * 8);
      float4 xa = x4[0], xb = x4[1];
      float4 ka = k4[0], kb = k4[1], va = v4[0], vb = v4[1];
      float ak = sm[binO + 8 + h], av = sm[binO + 16 + h];
      ak = fmaf(xa.x, ka.x, ak); av = fmaf(xa.x, va.x, av);
      ak = fmaf(xa.y, ka.y, ak); av = fmaf(xa.y, va.y, av);
      ak = fmaf(xa.z, ka.z, ak); av = fmaf(xa.z, va.z, av);
      ak = fmaf(xa.w, ka.w, ak); av = fmaf(xa.w, va.w, av);
      ak = fmaf(xb.x, kb.x, ak); av = fmaf(xb.x, vb.x, av);
      ak = fmaf(xb.y, kb.y, ak); av = fmaf(xb.y, vb.y, av);
      ak = fmaf(xb.z, kb.z, ak); av = fmaf(xb.z, vb.z, av);
      ak = fmaf(xb.w, kb.w, ak); av = fmaf(xb.w, vb.w, av);
      *(float2*)(sm + OFF_KVP + r * 16 + h * 2) = make_float2(ak, av);
    }
    __syncthreads();

    // attention (no max pass: softmax is shift-invariant, scores bounded) + fused out-proj/LN
    if (tid < d.Lq * 8) {
      int e = tid & 7, qi = tid >> 3;
      float q2 = sm[OFF_QP + tid];
      const float* kvp = sm + OFF_KVP + 2 * e;
      float l = 0.f, acc = 0.f;
      #pragma unroll 2
      for (int k = 0; k < d.Lk; k++) {
        float2 kv = *(const float2*)(kvp + k * 16);
        float ex = EXP2F(q2 * kv.x);
        l += ex;
        acc = fmaf(ex, kv.y, acc);
      }
      float ov = acc * __builtin_amdgcn_rcpf(l);
      // out-projection via intra-8-lane shuffles (ov for all h lives in this 8-group)
      int lb = (tid & 63) & ~7;
      const float4* wo4 = (const float4*)(sm + woutO + e * 8);
      float4 woa = wo4[0], wob = wo4[1];
      float a = sm[boutO + e];
      a = fmaf(__shfl(ov, lb + 0), woa.x, a);
      a = fmaf(__shfl(ov, lb + 1), woa.y, a);
      a = fmaf(__shfl(ov, lb + 2), woa.z, a);
      a = fmaf(__shfl(ov, lb + 3), woa.w, a);
      a = fmaf(__shfl(ov, lb + 4), wob.x, a);
      a = fmaf(__shfl(ov, lb + 5), wob.y, a);
      a = fmaf(__shfl(ov, lb + 6), wob.z, a);
      a = fmaf(__shfl(ov, lb + 7), wob.w, a);
      if (d.dst1 >= 0) {
        float mu = grp8_sum(a) * 0.125f;
        float dd = a - mu;
        float var = grp8_sum(dd * dd) * 0.125f;
        float nv = fmaf(dd * rsqrtf(var + 1e-5f), sm[OFF_NG + e], sm[OFF_NB + e]);
        sm[OFF_CAT + (d.dst1 + qi) * 8 + e] += nv;
        if (d.dst2 >= 0) sm[OFF_CAT + (d.dst2 + qi) * 8 + e] += nv;
      } else {
        sm[OFF_QP + tid] = a;  // final MHA raw output (32,8); safe: each lane re-reads only its own QP slot
      }
    }
    __syncthreads();
  }

  // ---------- phase 3: fc1 + channel softmax ----------
  if (tid < 90) {
    float acc = sm[OFF_FC1B + tid];
    float acc2 = 0.f;
    const float4* w4 = (const float4*)(fc1_w + tid * 256);
    #pragma unroll 4
    for (int k = 0; k < 64; k += 2) {
      float4 w0 = w4[k], w1 = w4[k + 1];
      float4 o0 = *(const float4*)(sm + OFF_QP + k * 4);
      float4 o1 = *(const float4*)(sm + OFF_QP + k * 4 + 4);
      acc  = fmaf(o0.x, w0.x, acc);  acc  = fmaf(o0.y, w0.y, acc);
      acc  = fmaf(o0.z, w0.z, acc);  acc  = fmaf(o0.w, w0.w, acc);
      acc2 = fmaf(o1.x, w1.x, acc2); acc2 = fmaf(o1.y, w1.y, acc2);
      acc2 = fmaf(o1.z, w1.z, acc2); acc2 = fmaf(o1.w, w1.w, acc2);
    }
    sm[OFF_FCO + tid] = acc + acc2;
  }
  __syncthreads();
  if (tid < 30) {
    float x0 = sm[OFF_FCO + 3 * tid], x1 = sm[OFF_FCO + 3 * tid + 1], x2 = sm[OFF_FCO + 3 * tid + 2];
    float m = fmaxf(x0, fmaxf(x1, x2));
    float e0 = __expf(x0 - m), e1 = __expf(x1 - m), e2 = __expf(x2 - m);
    float inv = __builtin_amdgcn_rcpf(e0 + e1 + e2);
    float* op = out + (size_t)b * 90;
    op[tid]      = e0 * inv;
    op[30 + tid] = e1 * inv;
    op[60 + tid] = e2 * inv;
  }
#undef CP
#undef CPQ
}

extern "C" void kernel_launch(void* const* d_in, const int* in_sizes, int n_in,
                              void* d_out, int out_size, void* d_ws, size_t ws_size,
                              hipStream_t stream) {
  (void)n_in; (void)out_size; (void)d_ws; (void)ws_size;
  int B = in_sizes[0] / 4720;  // eeg = (B,2,20,118)
  cmt_kernel<<<B, NT, 0, stream>>>(
      (const float*)d_in[0],  (const float*)d_in[1],  (const float*)d_in[2],
      (const float*)d_in[3],  (const float*)d_in[4],  (const float*)d_in[5],
      (const float*)d_in[6],  (const float*)d_in[7],  (const float*)d_in[8],
      (const float*)d_in[9],  (const float*)d_in[10], (const float*)d_in[11],
      (const float*)d_in[12], (const float*)d_in[13], (const float*)d_in[14],
      (const float*)d_in[15], (const float*)d_in[16], (const float*)d_in[17],
      (const float*)d_in[18], (const float*)d_in[19], (const float*)d_in[20],
      (const float*)d_in[21], (const float*)d_in[22], (const float*)d_in[23],
      (const float*)d_in[24], (const float*)d_in[25], (const float*)d_in[26],
      (const float*)d_in[27], (const float*)d_in[28], (const float*)d_in[29],
      (float*)d_out);
}

// Round 3
// 299.502 us; speedup vs baseline: 1.7992x; 1.3646x over previous
//
#include <hip/hip_runtime.h>
#include <cstdint>
#include <cstddef>

#define NT 256
#define LOG2E 1.4426950408889634f

#if defined(__has_builtin)
#  if __has_builtin(__builtin_amdgcn_exp2f)
#    define EXP2F(x) __builtin_amdgcn_exp2f(x)
#  else
#    define EXP2F(x) exp2f(x)
#  endif
#else
#  define EXP2F(x) exp2f(x)
#endif

// ---------------- shared-memory layout (float offsets) ----------------
enum {
  OFF_EEGB = 0,       // 8
  OFF_PSAW = 8,       // 16
  OFF_PSAB = 24,      // 8
  OFF_LOCW = 32,      // 24
  OFF_LOCB = 56,      // 8
  OFF_TGTW = 64,      // 8
  OFF_TGTB = 72,      // 8
  OFF_NG   = 80,      // 8
  OFF_NB   = 88,      // 8
  OFF_CINW = 96,      // 192 (q-rows pre-scaled by log2e)
  OFF_CINB = 288,     // 24
  OFF_COUTW= 312,     // 64
  OFF_COUTB= 376,     // 8
  OFF_SINW = 384,     // 192
  OFF_SINB = 576,     // 24
  OFF_SOUTW= 600,     // 64
  OFF_SOUTB= 664,     // 8
  OFF_OINW = 672,     // 192
  OFF_OINB = 864,     // 24
  OFF_OOUTW= 888,     // 64
  OFF_OOUTB= 952,     // 8
  OFF_FC1B = 960,     // 90 -> 1050
  OFF_PE30 = 1052,    // 8
  OFF_PE32 = 1060,    // 8 -> 1068
  OFF_Ebuf = 1068,    // 240
  OFF_Pbuf = 1308,    // 256
  OFF_Sbuf = 1564,    // 256
  OFF_Abuf = 1820,    // 256
  OFF_Lbuf = 2076,    // 256
  OFF_Tbuf = 2332,    // 256
  OFF_CAT  = 2588,    // 1008 -> 3596
  OFF_QP   = 3596,    // 256 (ov exchange; final raw output for fc1)
  OFF_KS   = 3852,    // 8*68 = 544 (k, h-major, padded stride 68)
  OFF_VS   = 4396,    // 544
  OFF_FCO  = 4940,    // 90 -> 5030
  SM_TOTAL = 5032,    // 20128 B -> 8 blocks/CU
  OFF_EEGW = OFF_KS,  // 640 floats, aliased: dead before first kv-proj
};

struct MhaDesc { int Lq, Lk, kstart, qoff, kvoff, wset, dst1, dst2, flags; };
// flags: bit0 = first pass (project q, zero accumulators); bit1 = last pass (finalize)

#define EB 0
#define PB 30
#define AB 62
#define SB 94
static __device__ const MhaDesc g_desc[20] = {
  {30, 32, 0, OFF_Ebuf, OFF_Pbuf, 0, EB, -1, 3},   // cross(e,p)
  {30, 32, 0, OFF_Ebuf, OFF_Abuf, 0, EB, -1, 3},   // cross(e,a)
  {30, 32, 0, OFF_Ebuf, OFF_Lbuf, 0, EB, -1, 3},   // cross(e,l)
  {30, 30, 0, OFF_Ebuf, OFF_Ebuf, 1, EB, -1, 3},   // selfa(e)
  {30, 32, 0, OFF_Ebuf, OFF_Sbuf, 0, EB, -1, 3},   // cross(e,s)
  {32, 30, 0, OFF_Pbuf, OFF_Ebuf, 0, PB, -1, 3},   // cross(p,e)
  {32, 32, 0, OFF_Pbuf, OFF_Abuf, 0, PB, -1, 3},   // cross(p,a)
  {32, 32, 0, OFF_Pbuf, OFF_Lbuf, 0, PB, -1, 3},   // cross(p,l)
  {32, 32, 0, OFF_Pbuf, OFF_Pbuf, 1, PB, -1, 3},   // selfa(p)
  {32, 32, 0, OFF_Pbuf, OFF_Sbuf, 0, PB, -1, 3},   // cross(p,s)
  {32, 30, 0, OFF_Sbuf, OFF_Ebuf, 0, SB, -1, 3},   // cross(s,e)
  {32, 32, 0, OFF_Sbuf, OFF_Pbuf, 0, SB, -1, 3},   // cross(s,p)
  {32, 32, 0, OFF_Sbuf, OFF_Abuf, 0, SB, -1, 3},   // cross(s,a)
  {32, 32, 0, OFF_Sbuf, OFF_Lbuf, 0, SB, AB, 3},   // cross(s,l) -> speech AND action
  {32, 30, 0, OFF_Abuf, OFF_Ebuf, 0, AB, -1, 3},   // cross(a,e)
  {32, 32, 0, OFF_Abuf, OFF_Pbuf, 0, AB, -1, 3},   // cross(a,p)
  {32, 32, 0, OFF_Abuf, OFF_Abuf, 1, AB, -1, 3},   // selfa(a)
  {32, 32, 0, OFF_Abuf, OFF_Sbuf, 0, AB, -1, 3},   // cross(a,s)
  {32, 64, 0,  OFF_Tbuf, OFF_CAT, 2, -1, -1, 1},   // final MHA pass 1 (k 0..63)
  {32, 62, 64, OFF_Tbuf, OFF_CAT, 2, -1, -1, 2},   // final MHA pass 2 (k 64..125)
};

__device__ __forceinline__ float grp8_sum(float v) {
  v += __shfl_xor(v, 1);
  v += __shfl_xor(v, 2);
  v += __shfl_xor(v, 4);
  return v;
}

__global__ __launch_bounds__(NT, 8) void cmt_kernel(
    const float* __restrict__ eeg, const float* __restrict__ pupil,
    const float* __restrict__ speech, const float* __restrict__ action,
    const float* __restrict__ location, const float* __restrict__ tgt,
    const float* __restrict__ eeg_w, const float* __restrict__ eeg_b,
    const float* __restrict__ psa_w, const float* __restrict__ psa_b,
    const float* __restrict__ loc_w, const float* __restrict__ loc_b,
    const float* __restrict__ tgt_w, const float* __restrict__ tgt_b,
    const float* __restrict__ ng, const float* __restrict__ nb,
    const float* __restrict__ cin_w, const float* __restrict__ cin_b,
    const float* __restrict__ cout_w, const float* __restrict__ cout_b,
    const float* __restrict__ sin_w, const float* __restrict__ sin_b,
    const float* __restrict__ sout_w, const float* __restrict__ sout_b,
    const float* __restrict__ oin_w, const float* __restrict__ oin_b,
    const float* __restrict__ oout_w, const float* __restrict__ oout_b,
    const float* __restrict__ fc1_w, const float* __restrict__ fc1_b,
    float* __restrict__ out)
{
  __shared__ float sm[SM_TOTAL];
  const int tid = threadIdx.x;
  const int b = blockIdx.x;

#define CP(off, p, n) for (int i = tid; i < (n); i += NT) sm[(off)+i] = (p)[i]
#define CPQ(off, p, n, nq) for (int i = tid; i < (n); i += NT) sm[(off)+i] = (p)[i] * ((i < (nq)) ? LOG2E : 1.0f)

  // ---------- phase 0: stage weights ----------
  // eeg weights transposed into the (not-yet-used) K/V scratch region
  for (int i = tid; i < 640; i += NT) sm[OFF_EEGW + i] = eeg_w[(i & 7) * 80 + (i >> 3)];
  CP(OFF_EEGB, eeg_b, 8);
  CP(OFF_PSAW, psa_w, 16);   CP(OFF_PSAB, psa_b, 8);
  CP(OFF_LOCW, loc_w, 24);   CP(OFF_LOCB, loc_b, 8);
  CP(OFF_TGTW, tgt_w, 8);    CP(OFF_TGTB, tgt_b, 8);
  CP(OFF_NG, ng, 8);         CP(OFF_NB, nb, 8);
  CPQ(OFF_CINW, cin_w, 192, 64);  CPQ(OFF_CINB, cin_b, 24, 8);
  CP(OFF_COUTW, cout_w, 64); CP(OFF_COUTB, cout_b, 8);
  CPQ(OFF_SINW, sin_w, 192, 64);  CPQ(OFF_SINB, sin_b, 24, 8);
  CP(OFF_SOUTW, sout_w, 64); CP(OFF_SOUTB, sout_b, 8);
  CPQ(OFF_OINW, oin_w, 192, 64);  CPQ(OFF_OINB, oin_b, 24, 8);
  CP(OFF_OOUTW, oout_w, 64); CP(OFF_OOUTB, oout_b, 8);
  CP(OFF_FC1B, fc1_b, 90);
  for (int i = tid; i < 1008; i += NT) sm[OFF_CAT + i] = 0.f;
  if (tid < 16) {
    const float divs[4] = {1.f, 0.1f, 0.01f, 0.001f};
    float pos = (tid < 8) ? 30.f : 32.f;
    int e = tid & 7;
    float x = pos * divs[e >> 1];
    float v = (e & 1) ? cosf(x) : sinf(x);
    sm[((tid < 8) ? OFF_PE30 : OFF_PE32) + e] = v;
  }
  __syncthreads();

  // ---------- phase 1: convs + positional encoding ----------
  if (tid < 240) {  // eeg conv2d -> e[30][8]
    int w = tid >> 3, o = tid & 7;
    const float* ep = eeg + (size_t)b * 4720 + 4 * w;
    const float* wt = sm + OFF_EEGW + o;
    float acc = sm[OFF_EEGB + o];
    #pragma unroll
    for (int i = 0; i < 2; i++)
      #pragma unroll
      for (int kh = 0; kh < 20; kh++) {
        float2 x = *(const float2*)(ep + i * 2360 + kh * 118);
        int ik = i * 20 + kh;
        acc = fmaf(x.x, wt[ik * 16], fmaf(x.y, wt[ik * 16 + 8], acc));
      }
    sm[OFF_Ebuf + w * 8 + o] = acc + sm[OFF_PE30 + o];
  }
  {  // conv1d k=1 pad=1 -> length-32 sequences, + pe32
    int t = tid >> 3, o = tid & 7;
    bool inb = (t >= 1 && t <= 30);
    int ti = t - 1;
    float pe = sm[OFF_PE32 + o];
    float w0 = sm[OFF_PSAW + 2 * o], w1 = sm[OFF_PSAW + 2 * o + 1];
    float pb = sm[OFF_PSAB + o];
    float vp = pb, vs = pb, va = pb;
    float vl = sm[OFF_LOCB + o], vt = sm[OFF_TGTB + o];
    if (inb) {
      const float* pp = pupil    + (size_t)b * 60 + ti;
      const float* sp = speech   + (size_t)b * 60 + ti;
      const float* ap = action   + (size_t)b * 60 + ti;
      const float* lp = location + (size_t)b * 90 + ti;
      vp = fmaf(pp[0], w0, fmaf(pp[30], w1, vp));
      vs = fmaf(sp[0], w0, fmaf(sp[30], w1, vs));
      va = fmaf(ap[0], w0, fmaf(ap[30], w1, va));
      vl = fmaf(lp[0],  sm[OFF_LOCW + 3 * o],     vl);
      vl = fmaf(lp[30], sm[OFF_LOCW + 3 * o + 1], vl);
      vl = fmaf(lp[60], sm[OFF_LOCW + 3 * o + 2], vl);
      vt = fmaf(tgt[(size_t)b * 30 + ti], sm[OFF_TGTW + o], vt);
    }
    sm[OFF_Pbuf + tid] = vp + pe;
    sm[OFF_Sbuf + tid] = vs + pe;
    sm[OFF_Abuf + tid] = va + pe;
    sm[OFF_Lbuf + tid] = vl + pe;
    sm[OFF_Tbuf + tid] = vt + pe;
  }
  __syncthreads();

  // ---------- phase 2: 19 MHAs (final one in 2 accumulate passes) ----------
  float q_reg = 0.f, l0 = 0.f, l1 = 0.f, a0 = 0.f, a1 = 0.f;
  for (int mi = 0; mi < 20; mi++) {
    const MhaDesc d = g_desc[mi];
    int winO, binO, woutO, boutO;
    if (d.wset == 0)      { winO = OFF_CINW; binO = OFF_CINB; woutO = OFF_COUTW; boutO = OFF_COUTB; }
    else if (d.wset == 1) { winO = OFF_SINW; binO = OFF_SINB; woutO = OFF_SOUTW; boutO = OFF_SOUTB; }
    else                  { winO = OFF_OINW; binO = OFF_OINB; woutO = OFF_OOUTW; boutO = OFF_OOUTB; }

    // q projection -> register (weights pre-scaled by log2e)
    if ((d.flags & 1) && tid < d.Lq * 8) {
      int r = tid >> 3, h = tid & 7;
      const float4* x4 = (const float4*)(sm + d.qoff + r * 8);
      const float4* w4 = (const float4*)(sm + winO + h * 8);
      float4 xa = x4[0], xb = x4[1], wa = w4[0], wb = w4[1];
      float a = sm[binO + h];
      a = fmaf(xa.x, wa.x, a); a = fmaf(xa.y, wa.y, a);
      a = fmaf(xa.z, wa.z, a); a = fmaf(xa.w, wa.w, a);
      a = fmaf(xb.x, wb.x, a); a = fmaf(xb.y, wb.y, a);
      a = fmaf(xb.z, wb.z, a); a = fmaf(xb.w, wb.w, a);
      q_reg = a;
    }
    // k,v projection into h-major padded arrays
    for (int idx = tid; idx < d.Lk * 8; idx += NT) {
      int r = idx >> 3, h = idx & 7;
      const float4* x4 = (const float4*)(sm + d.kvoff + (d.kstart + r) * 8);
      const float4* k4 = (const float4*)(sm + winO + 64 + h * 8);
      const float4* v4 = (const float4*)(sm + winO + 128 + h * 8);
      float4 xa = x4[0], xb = x4[1];
      float4 ka = k4[0], kb = k4[1], va = v4[0], vb = v4[1];
      float ak = sm[binO + 8 + h], av = sm[binO + 16 + h];
      ak = fmaf(xa.x, ka.x, ak); av = fmaf(xa.x, va.x, av);
      ak = fmaf(xa.y, ka.y, ak); av = fmaf(xa.y, va.y, av);
      ak = fmaf(xa.z, ka.z, ak); av = fmaf(xa.z, va.z, av);
      ak = fmaf(xa.w, ka.w, ak); av = fmaf(xa.w, va.w, av);
      ak = fmaf(xb.x, kb.x, ak); av = fmaf(xb.x, vb.x, av);
      ak = fmaf(xb.y, kb.y, ak); av = fmaf(xb.y, vb.y, av);
      ak = fmaf(xb.z, kb.z, ak); av = fmaf(xb.z, vb.z, av);
      ak = fmaf(xb.w, kb.w, ak); av = fmaf(xb.w, vb.w, av);
      sm[OFF_KS + h * 68 + r] = ak;
      sm[OFF_VS + h * 68 + r] = av;
    }
    __syncthreads();

    // attention (no max pass; 2x2 partial accumulators for ILP)
    if (tid < d.Lq * 8) {
      int e = tid & 7;
      if (d.flags & 1) { l0 = 0.f; l1 = 0.f; a0 = 0.f; a1 = 0.f; }
      const float* Kp = sm + OFF_KS + e * 68;
      const float* Vp = sm + OFF_VS + e * 68;
      int n4 = d.Lk >> 2;
      for (int k4 = 0; k4 < n4; k4++) {
        float4 kk = *(const float4*)(Kp + 4 * k4);
        float4 vv = *(const float4*)(Vp + 4 * k4);
        float e0 = EXP2F(q_reg * kk.x);
        float e1 = EXP2F(q_reg * kk.y);
        float e2 = EXP2F(q_reg * kk.z);
        float e3 = EXP2F(q_reg * kk.w);
        l0 += e0; l1 += e1;
        a0 = fmaf(e0, vv.x, a0); a1 = fmaf(e1, vv.y, a1);
        l0 += e2; l1 += e3;
        a0 = fmaf(e2, vv.z, a0); a1 = fmaf(e3, vv.w, a1);
      }
      for (int k = n4 * 4; k < d.Lk; k++) {
        float ex = EXP2F(q_reg * Kp[k]);
        l0 += ex; a0 = fmaf(ex, Vp[k], a0);
      }
      if (d.flags & 2) {
        float ov = (a0 + a1) * __builtin_amdgcn_rcpf(l0 + l1);
        // 8-group exchange through LDS (same wave -> no barrier needed)
        sm[OFF_QP + tid] = ov;
        int gb = tid & ~7;
        float4 o0 = *(const float4*)(sm + OFF_QP + gb);
        float4 o1 = *(const float4*)(sm + OFF_QP + gb + 4);
        const float4* wo4 = (const float4*)(sm + woutO + e * 8);
        float4 woa = wo4[0], wob = wo4[1];
        float a = sm[boutO + e];
        a = fmaf(o0.x, woa.x, a); a = fmaf(o0.y, woa.y, a);
        a = fmaf(o0.z, woa.z, a); a = fmaf(o0.w, woa.w, a);
        a = fmaf(o1.x, wob.x, a); a = fmaf(o1.y, wob.y, a);
        a = fmaf(o1.z, wob.z, a); a = fmaf(o1.w, wob.w, a);
        if (d.dst1 >= 0) {
          int qi = tid >> 3;
          float mu = grp8_sum(a) * 0.125f;
          float dd = a - mu;
          float var = grp8_sum(dd * dd) * 0.125f;
          float nv = fmaf(dd * rsqrtf(var + 1e-5f), sm[OFF_NG + e], sm[OFF_NB + e]);
          sm[OFF_CAT + (d.dst1 + qi) * 8 + e] += nv;
          if (d.dst2 >= 0) sm[OFF_CAT + (d.dst2 + qi) * 8 + e] += nv;
        } else {
          sm[OFF_QP + tid] = a;  // final MHA raw output (32,8) for fc1
        }
      }
    }
    __syncthreads();
  }

  // ---------- phase 3: fc1 (2 threads per output) + channel softmax ----------
  if (tid < 180) {
    int j = tid >> 1, p = tid & 1;
    const float4* w4 = (const float4*)(fc1_w + j * 256);
    const float4* o4 = (const float4*)(sm + OFF_QP);
    float acc = 0.f;
    #pragma unroll 8
    for (int c = p; c < 64; c += 2) {
      float4 w = w4[c], o = o4[c];
      acc = fmaf(o.x, w.x, acc); acc = fmaf(o.y, w.y, acc);
      acc = fmaf(o.z, w.z, acc); acc = fmaf(o.w, w.w, acc);
    }
    acc += __shfl_xor(acc, 1);
    if (p == 0) sm[OFF_FCO + j] = acc + sm[OFF_FC1B + j];
  }
  __syncthreads();
  if (tid < 30) {
    float x0 = sm[OFF_FCO + 3 * tid], x1 = sm[OFF_FCO + 3 * tid + 1], x2 = sm[OFF_FCO + 3 * tid + 2];
    float m = fmaxf(x0, fmaxf(x1, x2));
    float e0 = __expf(x0 - m), e1 = __expf(x1 - m), e2 = __expf(x2 - m);
    float inv = __builtin_amdgcn_rcpf(e0 + e1 + e2);
    float* op = out + (size_t)b * 90;
    op[tid]      = e0 * inv;
    op[30 + tid] = e1 * inv;
    op[60 + tid] = e2 * inv;
  }
#undef CP
#undef CPQ
}

extern "C" void kernel_launch(void* const* d_in, const int* in_sizes, int n_in,
                              void* d_out, int out_size, void* d_ws, size_t ws_size,
                              hipStream_t stream) {
  (void)n_in; (void)out_size; (void)d_ws; (void)ws_size;
  int B = in_sizes[0] / 4720;  // eeg = (B,2,20,118)
  cmt_kernel<<<B, NT, 0, stream>>>(
      (const float*)d_in[0],  (const float*)d_in[1],  (const float*)d_in[2],
      (const float*)d_in[3],  (const float*)d_in[4],  (const float*)d_in[5],
      (const float*)d_in[6],  (const float*)d_in[7],  (const float*)d_in[8],
      (const float*)d_in[9],  (const float*)d_in[10], (const float*)d_in[11],
      (const float*)d_in[12], (const float*)d_in[13], (const float*)d_in[14],
      (const float*)d_in[15], (const float*)d_in[16], (const float*)d_in[17],
      (const float*)d_in[18], (const float*)d_in[19], (const float*)d_in[20],
      (const float*)d_in[21], (const float*)d_in[22], (const float*)d_in[23],
      (const float*)d_in[24], (const float*)d_in[25], (const float*)d_in[26],
      (const float*)d_in[27], (const float*)d_in[28], (const float*)d_in[29],
      (float*)d_out);
}